// Round 3
// baseline (95.034 us; speedup 1.0000x reference)
//
#include <hip/hip_runtime.h>
#include <math.h>

#define BB 4
#define CC 256
#define HW (128*128)
#define NLINES 1024          // HW / 16 pixels-per-64B-line
#define NC 19
#define NV 50
#define PP (NC*NV)           // 950
#define INV_T (1.0f/0.07f)
#define PLANE ((size_t)BB * PP * CC)   // elems per bf16 plane
#define RT 60                // row tiles of 16 (60*16=960 >= 950)
#define CG 4                 // column groups
#define TPG 15               // col tiles per group (4*15=60)

typedef short bf16x8 __attribute__((ext_vector_type(8)));
typedef float f32x4  __attribute__((ext_vector_type(4)));

static __device__ __forceinline__ unsigned short f2bf(float f) {
    unsigned int u = __float_as_uint(f);
    unsigned int r = (u + 0x7fffu + ((u >> 16) & 1u)) >> 16;   // RNE
    return (unsigned short)r;
}
static __device__ __forceinline__ float bf2f(unsigned short h) {
    return __uint_as_float(((unsigned int)h) << 16);
}
__device__ __forceinline__ void lse_merge(float& m, float& s, float m2, float s2) {
    float nm = fmaxf(m, m2);
    float d1 = m - nm;  d1 = (d1 < 0.f) ? d1 : 0.f;   // clamp kills NaN from inf-inf
    float d2 = m2 - nm; d2 = (d2 < 0.f) ? d2 : 0.f;
    s = s * __expf(d1) + s2 * __expf(d2);
    m = nm;
}

// ---------- setup kernels (all tiny, rebuilt every launch: ws is poisoned) ----------

__global__ __launch_bounds__(256)
void init_kernel(long long* __restrict__ map8, unsigned int* __restrict__ bitmap,
                 int* __restrict__ counts) {
    int i = blockIdx.x * 256 + threadIdx.x;       // 64 blocks -> 16384 threads
    map8[i] = -1LL;                               // 4 shorts of -1 each
    if (blockIdx.x == 0) {
        if (threadIdx.x < BB * 32) bitmap[threadIdx.x] = 0u;
        if (threadIdx.x < BB) counts[threadIdx.x] = 0;
    }
}

__global__ __launch_bounds__(256)
void scatter_kernel(const int* __restrict__ sidx, short* __restrict__ map,
                    unsigned int* __restrict__ bitmap) {
    int i = blockIdx.x * 256 + threadIdx.x;
    if (i >= BB * PP) return;
    int b = i / PP, p = i - b * PP;
    int pix = sidx[i];
    map[(size_t)b * HW + pix] = (short)p;
    atomicOr(&bitmap[b * 32 + (pix >> 9)], 1u << ((pix >> 4) & 31));
}

__global__ __launch_bounds__(1024)
void listbuild_kernel(const unsigned int* __restrict__ bitmap,
                      unsigned short* __restrict__ list, int* __restrict__ counts) {
    int b = blockIdx.x;
    int tid = threadIdx.x;                        // 1024 threads = 16 waves
    int lane = tid & 63, wv = tid >> 6;
    unsigned int word = bitmap[b * 32 + (tid >> 5)];
    int bit = (word >> (tid & 31)) & 1;
    unsigned long long mask = __ballot(bit);
    int rank = __popcll(mask & ((1ull << lane) - 1ull));
    int wcnt = __popcll(mask);
    __shared__ int wbase[16];
    if (lane == 0) wbase[wv] = wcnt;
    __syncthreads();
    if (tid == 0) {
        int acc = 0;
        for (int w = 0; w < 16; ++w) { int t = wbase[w]; wbase[w] = acc; acc += t; }
        counts[b] = acc;
    }
    __syncthreads();
    if (bit) list[b * NLINES + wbase[wv] + rank] = (unsigned short)tid;
}

// ---------- line-granular gather: one block per (b, tensor, channel) ----------
__global__ __launch_bounds__(256)
void gather_kernel(const float* __restrict__ fq, const float* __restrict__ fk,
                   const short* __restrict__ map, const unsigned short* __restrict__ list,
                   const int* __restrict__ counts,
                   unsigned short* __restrict__ xqh, unsigned short* __restrict__ xql,
                   unsigned short* __restrict__ xkh, unsigned short* __restrict__ xkl) {
    __shared__ short mapl[HW / 16 * 16];          // 16384 shorts = 32 KB
    __shared__ unsigned short llist[NLINES];      // 2 KB

    int b = blockIdx.y;
    int id = blockIdx.x;                          // 0..511
    int tensor = id >> 8;
    int cid = id & 255;
    // swizzle: all 32 channels of an output 64B line land on the same XCD (id&7)
    int c = ((cid & 7) << 5) | (cid >> 3);

    const float* src = (tensor ? fk : fq) + ((size_t)b * CC + c) * HW;
    unsigned short* oh = (tensor ? xkh : xqh);
    unsigned short* ol = (tensor ? xkl : xql);

    int tid = threadIdx.x;
    // stage map (16B per copy) and list
    const int4* mg = (const int4*)(map + (size_t)b * HW);
    int4* ml = (int4*)mapl;
#pragma unroll
    for (int j = 0; j < 8; ++j) ml[tid + j * 256] = mg[tid + j * 256];
    const int* lg = (const int*)(list + b * NLINES);
    int* ll = (int*)llist;
    ll[tid] = lg[tid];
    ll[tid + 256] = lg[tid + 256];
    __syncthreads();

    int L = counts[b];
    int sub = tid & 15, iw = tid >> 4;            // 16 lines per 256-thread iteration

    for (int i0 = iw; i0 < L; i0 += 64) {
        float v[4]; int px[4]; bool ok[4];
#pragma unroll
        for (int j = 0; j < 4; ++j) {
            int i = i0 + j * 16;
            ok[j] = (i < L);
            int line = llist[ok[j] ? i : 0];
            px[j] = line * 16 + sub;
            v[j] = src[px[j]];                    // 4 independent loads in flight
        }
#pragma unroll
        for (int j = 0; j < 4; ++j) {
            if (!ok[j]) continue;
            int slot = mapl[px[j]];
            if (slot >= 0) {
                unsigned short h = f2bf(v[j]);
                size_t dst = ((size_t)b * PP + slot) * CC + c;
                oh[dst] = h;
                ol[dst] = f2bf(v[j] - bf2f(h));
            }
        }
    }
}

// ---------- MFMA Gram + masked online-LSE, column-split 4 ways ----------
__global__ __launch_bounds__(512)
void nce_mfma(const unsigned short* __restrict__ xqh, const unsigned short* __restrict__ xql,
              const unsigned short* __restrict__ xkh, const unsigned short* __restrict__ xkl,
              float* __restrict__ pos, float* __restrict__ pm, float* __restrict__ ps) {
    __shared__ float red_m[8][16];
    __shared__ float red_s[8][16];

    int b  = blockIdx.z;
    int cg = blockIdx.y;
    int r0 = blockIdx.x * 16;
    int tid = threadIdx.x;
    int w = tid >> 6, l = tid & 63;
    int lr = l & 15, lg = l >> 4;

    int arow = r0 + lr; if (arow > PP - 1) arow = PP - 1;
    size_t abase = ((size_t)b * PP + arow) * CC + lg * 8;
    bf16x8 Ah[8], Al[8];
#pragma unroll
    for (int kt = 0; kt < 8; ++kt) {
        Ah[kt] = *(const bf16x8*)(xqh + abase + kt * 32);
        Al[kt] = *(const bf16x8*)(xql + abase + kt * 32);
    }

    int   rcls[4]; bool rok[4];
    float m[4], s[4];
#pragma unroll
    for (int j = 0; j < 4; ++j) {
        int row = r0 + lg * 4 + j;
        rok[j] = (row < PP);
        rcls[j] = row / NV;
        m[j] = -INFINITY; s[j] = 0.f;
    }

    for (int tt = w; tt < TPG; tt += 8) {
        int t = cg * TPG + tt;
        int n0 = t * 16;
        int brow = n0 + lr; if (brow > PP - 1) brow = PP - 1;
        size_t bbase = ((size_t)b * PP + brow) * CC + lg * 8;
        bf16x8 Bh[8], Bl[8];
#pragma unroll
        for (int kt = 0; kt < 8; ++kt) {
            Bh[kt] = *(const bf16x8*)(xkh + bbase + kt * 32);
            Bl[kt] = *(const bf16x8*)(xkl + bbase + kt * 32);
        }
        f32x4 acc = {0.f, 0.f, 0.f, 0.f};
#pragma unroll
        for (int kt = 0; kt < 8; ++kt) {
            acc = __builtin_amdgcn_mfma_f32_16x16x32_bf16(Ah[kt], Bh[kt], acc, 0, 0, 0);
            acc = __builtin_amdgcn_mfma_f32_16x16x32_bf16(Ah[kt], Bl[kt], acc, 0, 0, 0);
            acc = __builtin_amdgcn_mfma_f32_16x16x32_bf16(Al[kt], Bh[kt], acc, 0, 0, 0);
        }

        int col = n0 + lr;
        bool colok = (col < PP);
        int ccls = col / NV;
#pragma unroll
        for (int j = 0; j < 4; ++j) {
            float x = acc[j] * INV_T;
            int row = r0 + lg * 4 + j;
            if (rok[j] && col == row) pos[(size_t)b * PP + row] = x;  // unique owner
            bool ok = rok[j] && colok && ((ccls != rcls[j]) || (col == row));
            if (ok) {
                if (x > m[j]) { s[j] = s[j] * __expf(m[j] - x) + 1.f; m[j] = x; }
                else          { s[j] += __expf(x - m[j]); }
            }
        }
    }

#pragma unroll
    for (int j = 0; j < 4; ++j) {
#pragma unroll
        for (int off = 1; off <= 8; off <<= 1) {
            float m2 = __shfl_xor(m[j], off, 64);
            float s2 = __shfl_xor(s[j], off, 64);
            lse_merge(m[j], s[j], m2, s2);
        }
    }
    if (lr == 0) {
#pragma unroll
        for (int j = 0; j < 4; ++j) { red_m[w][lg * 4 + j] = m[j]; red_s[w][lg * 4 + j] = s[j]; }
    }
    __syncthreads();

    if (tid < 16) {
        int row = r0 + tid;
        if (row < PP) {
            float mm = red_m[0][tid], ss = red_s[0][tid];
#pragma unroll
            for (int ww = 1; ww < 8; ++ww) lse_merge(mm, ss, red_m[ww][tid], red_s[ww][tid]);
            size_t o = ((size_t)b * CG + cg) * (RT * 16) + row;
            pm[o] = mm; ps[o] = ss;
        }
    }
}

__global__ __launch_bounds__(256)
void finalize_kernel(const float* __restrict__ pm, const float* __restrict__ ps,
                     const float* __restrict__ pos, float* __restrict__ out) {
    int i = blockIdx.x * 256 + threadIdx.x;
    if (i >= BB * PP) return;
    int b = i / PP, row = i - b * PP;
    float m = -INFINITY, s = 0.f;
#pragma unroll
    for (int g = 0; g < CG; ++g) {
        size_t o = ((size_t)b * CG + g) * (RT * 16) + row;
        lse_merge(m, s, pm[o], ps[o]);
    }
    out[i] = m + logf(s) - pos[i];
}

extern "C" void kernel_launch(void* const* d_in, const int* in_sizes, int n_in,
                              void* d_out, int out_size, void* d_ws, size_t ws_size,
                              hipStream_t stream) {
    const float* fq   = (const float*)d_in[0];
    const float* fk   = (const float*)d_in[1];
    const int*   sidx = (const int*)d_in[2];
    float* outp = (float*)d_out;

    char* p = (char*)d_ws;
    unsigned short* xqh = (unsigned short*)p; p += PLANE * 2;
    unsigned short* xql = (unsigned short*)p; p += PLANE * 2;
    unsigned short* xkh = (unsigned short*)p; p += PLANE * 2;
    unsigned short* xkl = (unsigned short*)p; p += PLANE * 2;
    short*          map = (short*)p;          p += (size_t)BB * HW * 2;
    unsigned int* bitmap = (unsigned int*)p;  p += BB * 32 * 4;
    int*         counts = (int*)p;            p += BB * 4;
    unsigned short* list = (unsigned short*)p; p += BB * NLINES * 2;
    float*          pos = (float*)p;          p += (size_t)BB * PP * 4;
    float*           pm = (float*)p;          p += (size_t)BB * CG * RT * 16 * 4;
    float*           ps = (float*)p;

    init_kernel<<<dim3(64), 256, 0, stream>>>((long long*)map, bitmap, counts);
    scatter_kernel<<<dim3((BB * PP + 255) / 256), 256, 0, stream>>>(sidx, map, bitmap);
    listbuild_kernel<<<dim3(BB), 1024, 0, stream>>>(bitmap, list, counts);
    gather_kernel<<<dim3(512, BB), 256, 0, stream>>>(fq, fk, map, list, counts,
                                                     xqh, xql, xkh, xkl);
    nce_mfma<<<dim3(RT, CG, BB), 512, 0, stream>>>(xqh, xql, xkh, xkl, pos, pm, ps);
    finalize_kernel<<<dim3((BB * PP + 255) / 256), 256, 0, stream>>>(pm, ps, pos, outp);
}

// Round 4
// 76.596 us; speedup vs baseline: 1.2407x; 1.2407x over previous
//
#include <hip/hip_runtime.h>
#include <math.h>

#define BB 4
#define CC 256
#define HW (128*128)
#define NLINES 1024          // HW / 16 pixels-per-64B-line
#define NC 19
#define NV 50
#define PP (NC*NV)           // 950
#define INV_T (1.0f/0.07f)
#define PLANE ((size_t)BB * PP * CC)   // elems per bf16 plane
#define RT 60                // row tiles of 16 (60*16=960 >= 950)
#define SRSTRIDE (960*16)    // per-b slotrec stride (shorts), 16B aligned

typedef short bf16x8 __attribute__((ext_vector_type(8)));
typedef float f32x4  __attribute__((ext_vector_type(4)));

static __device__ __forceinline__ unsigned short f2bf(float f) {
    unsigned int u = __float_as_uint(f);
    unsigned int r = (u + 0x7fffu + ((u >> 16) & 1u)) >> 16;   // RNE
    return (unsigned short)r;
}
static __device__ __forceinline__ float bf2f(unsigned short h) {
    return __uint_as_float(((unsigned int)h) << 16);
}
__device__ __forceinline__ void lse_merge(float& m, float& s, float m2, float s2) {
    float nm = fmaxf(m, m2);
    float d1 = m - nm;  d1 = (d1 < 0.f) ? d1 : 0.f;   // clamp kills NaN from inf-inf
    float d2 = m2 - nm; d2 = (d2 < 0.f) ? d2 : 0.f;
    s = s * __expf(d1) + s2 * __expf(d2);
    m = nm;
}

// ---------------- setup ----------------
__global__ __launch_bounds__(256)
void init_kernel(long long* __restrict__ map8, unsigned int* __restrict__ bitmap,
                 int* __restrict__ counts) {
    int i = blockIdx.x * 256 + threadIdx.x;       // 64 blocks -> 16384 * 8B = BB*HW shorts
    map8[i] = -1LL;
    if (blockIdx.x == 0) {
        if (threadIdx.x < BB * 32) bitmap[threadIdx.x] = 0u;
        if (threadIdx.x < BB) counts[threadIdx.x] = 0;
    }
}

__global__ __launch_bounds__(256)
void scatter_kernel(const int* __restrict__ sidx, short* __restrict__ map,
                    unsigned int* __restrict__ bitmap) {
    int i = blockIdx.x * 256 + threadIdx.x;
    if (i >= BB * PP) return;
    int b = i / PP, p = i - b * PP;
    int pix = sidx[i];
    map[(size_t)b * HW + pix] = (short)p;
    atomicOr(&bitmap[b * 32 + (pix >> 9)], 1u << ((pix >> 4) & 31));
}

// phase 1: compact sorted used-line list; phase 2: per-line 16-pixel slot records
__global__ __launch_bounds__(1024)
void listslot_kernel(const unsigned int* __restrict__ bitmap, const short* __restrict__ map,
                     unsigned short* __restrict__ list, short* __restrict__ slotrec,
                     int* __restrict__ counts) {
    __shared__ unsigned short lls[NLINES];
    __shared__ int wbase[16];
    __shared__ int Ls;
    int b = blockIdx.x;
    int tid = threadIdx.x;                        // tid == line number
    int lane = tid & 63, wv = tid >> 6;
    unsigned int word = bitmap[b * 32 + (tid >> 5)];
    int bit = (word >> (tid & 31)) & 1;
    unsigned long long mask = __ballot(bit);
    int rank = __popcll(mask & ((1ull << lane) - 1ull));
    if (lane == 0) wbase[wv] = __popcll(mask);
    __syncthreads();
    if (tid == 0) {
        int acc = 0;
        for (int w2 = 0; w2 < 16; ++w2) { int t = wbase[w2]; wbase[w2] = acc; acc += t; }
        counts[b] = acc; Ls = acc;
    }
    __syncthreads();
    if (bit) {
        int pos = wbase[wv] + rank;
        lls[pos] = (unsigned short)tid;
        list[b * NLINES + pos] = (unsigned short)tid;
    }
    __syncthreads();
    int L = Ls;
    for (int idx = tid; idx < L * 16; idx += 1024) {
        int li = idx >> 4, px = idx & 15;
        int ln = lls[li];
        slotrec[(size_t)b * SRSTRIDE + idx] = map[(size_t)b * HW + ln * 16 + px];
    }
}

// ---------------- gather: line-granular float4 streaming, 8 channels/block ----------------
__global__ __launch_bounds__(512)
void gather_kernel(const float* __restrict__ fq, const float* __restrict__ fk,
                   const unsigned short* __restrict__ list, const short* __restrict__ slotrec,
                   const int* __restrict__ counts,
                   unsigned short* __restrict__ xqh, unsigned short* __restrict__ xql,
                   unsigned short* __restrict__ xkh, unsigned short* __restrict__ xkl) {
    __shared__ short srec[SRSTRIDE / BB * 0 + 950 * 16];   // 950*16 shorts = 30400 B
    __shared__ unsigned short llist[NLINES];               // 2 KB

    int b = blockIdx.y;
    int id = blockIdx.x;                  // 0..63: tensor(1b) x channel-group(5b)
    int tensor = id >> 5;
    int c0 = (id & 31) * 8;

    const float* src = (tensor ? fk : fq) + ((size_t)b * CC + c0) * HW;
    unsigned short* oh = (tensor ? xkh : xqh);
    unsigned short* ol = (tensor ? xkl : xql);

    int tid = threadIdx.x;
    int L = counts[b];

    // stage list (1024 shorts) and slot records (L*16 shorts)
    ((int*)llist)[tid] = ((const int*)(list + b * NLINES))[tid];
    {
        int4* sl4 = (int4*)srec;
        const int4* sg4 = (const int4*)(slotrec + (size_t)b * SRSTRIDE);
        for (int i = tid; i < 2 * L; i += 512) sl4[i] = sg4[i];
    }
    __syncthreads();

    int lq = tid & 3;            // 16B quarter within the 64B line
    int li = tid >> 2;           // 0..127 line slot within a chunk

    for (int i0 = 0; i0 < 8; ++i0) {
        if (i0 * 128 >= L) break;
        int i = i0 * 128 + li;
        bool ok = (i < L);
        int ic = ok ? i : (L - 1);
        int line = llist[ic];
        const float* sb = src + line * 16 + lq * 4;
        float4 v[8];
#pragma unroll
        for (int ch = 0; ch < 8; ++ch)
            v[ch] = *(const float4*)(sb + ch * HW);
        if (ok) {
#pragma unroll
            for (int j = 0; j < 4; ++j) {
                int slot = srec[ic * 16 + lq * 4 + j];
                if (slot >= 0) {
                    unsigned int hw_[4], lw_[4];
#pragma unroll
                    for (int p = 0; p < 4; ++p) {
                        float a  = ((const float*)&v[2 * p])[j];
                        float c_ = ((const float*)&v[2 * p + 1])[j];
                        unsigned short ha = f2bf(a), hb = f2bf(c_);
                        float la = a  - bf2f(ha);
                        float lb = c_ - bf2f(hb);
                        hw_[p] = (unsigned int)ha | ((unsigned int)hb << 16);
                        lw_[p] = (unsigned int)f2bf(la) | ((unsigned int)f2bf(lb) << 16);
                    }
                    size_t dst = ((size_t)b * PP + slot) * CC + c0;
                    *(int4*)(oh + dst) = make_int4(hw_[0], hw_[1], hw_[2], hw_[3]);
                    *(int4*)(ol + dst) = make_int4(lw_[0], lw_[1], lw_[2], lw_[3]);
                }
            }
        }
    }
}

// ---------------- MFMA Gram + masked online-LSE, double-buffered B ----------------
#define LOADT(BUF, TT) do {                                                     \
    int n0_ = (TT) * 16;                                                        \
    int brow_ = n0_ + lr; if (brow_ > PP - 1) brow_ = PP - 1;                   \
    size_t bbase_ = ((size_t)b * PP + brow_) * CC + lg * 8;                     \
    _Pragma("unroll")                                                           \
    for (int kt = 0; kt < 8; ++kt) {                                            \
        Bh##BUF[kt] = *(const bf16x8*)(xkh + bbase_ + kt * 32);                 \
        Bl##BUF[kt] = *(const bf16x8*)(xkl + bbase_ + kt * 32);                 \
    }                                                                           \
} while (0)

#define COMPUTE(BUF, TT) do {                                                   \
    int n0_ = (TT) * 16;                                                        \
    f32x4 acc = {0.f, 0.f, 0.f, 0.f};                                           \
    _Pragma("unroll")                                                           \
    for (int kt = 0; kt < 8; ++kt) {                                            \
        acc = __builtin_amdgcn_mfma_f32_16x16x32_bf16(Ah[kt], Bh##BUF[kt], acc, 0, 0, 0); \
        acc = __builtin_amdgcn_mfma_f32_16x16x32_bf16(Ah[kt], Bl##BUF[kt], acc, 0, 0, 0); \
        acc = __builtin_amdgcn_mfma_f32_16x16x32_bf16(Al[kt], Bh##BUF[kt], acc, 0, 0, 0); \
    }                                                                           \
    int col = n0_ + lr;                                                         \
    bool colok = (col < PP);                                                    \
    int ccls = col / NV;                                                        \
    _Pragma("unroll")                                                           \
    for (int j = 0; j < 4; ++j) {                                               \
        float x = acc[j] * INV_T;                                               \
        int row = r0 + lg * 4 + j;                                              \
        if (rok[j] && col == row) pos_lds[lg * 4 + j] = x;                      \
        bool okm = rok[j] && colok && ((ccls != rcls[j]) || (col == row));      \
        if (okm) {                                                              \
            if (x > m[j]) { s[j] = s[j] * __expf(m[j] - x) + 1.f; m[j] = x; }   \
            else          { s[j] += __expf(x - m[j]); }                         \
        }                                                                       \
    }                                                                           \
} while (0)

__global__ __launch_bounds__(512)
void nce_mfma(const unsigned short* __restrict__ xqh, const unsigned short* __restrict__ xql,
              const unsigned short* __restrict__ xkh, const unsigned short* __restrict__ xkl,
              float* __restrict__ out) {
    __shared__ float pos_lds[16];
    __shared__ float red_m[8][16];
    __shared__ float red_s[8][16];

    int b  = blockIdx.x;
    int r0 = blockIdx.y * 16;
    int tid = threadIdx.x;
    int w = tid >> 6, l = tid & 63;
    int lr = l & 15, lg = l >> 4;

    int arow = r0 + lr; if (arow > PP - 1) arow = PP - 1;
    size_t abase = ((size_t)b * PP + arow) * CC + lg * 8;
    bf16x8 Ah[8], Al[8];
#pragma unroll
    for (int kt = 0; kt < 8; ++kt) {
        Ah[kt] = *(const bf16x8*)(xqh + abase + kt * 32);
        Al[kt] = *(const bf16x8*)(xql + abase + kt * 32);
    }

    int   rcls[4]; bool rok[4];
    float m[4], s[4];
#pragma unroll
    for (int j = 0; j < 4; ++j) {
        int row = r0 + lg * 4 + j;
        rok[j] = (row < PP);
        rcls[j] = row / NV;
        m[j] = -INFINITY; s[j] = 0.f;
    }

    bf16x8 BhA[8], BlA[8], BhB[8], BlB[8];
    int t = w;
    LOADT(A, t);
#pragma unroll
    for (int half = 0; half < 4; ++half) {
        if (t + 8 < RT) LOADT(B, t + 8);
        COMPUTE(A, t);
        t += 8;
        if (t >= RT) break;
        if (t + 8 < RT) LOADT(A, t + 8);
        COMPUTE(B, t);
        t += 8;
        if (t >= RT) break;
    }

#pragma unroll
    for (int j = 0; j < 4; ++j) {
#pragma unroll
        for (int off = 1; off <= 8; off <<= 1) {
            float m2 = __shfl_xor(m[j], off, 64);
            float s2 = __shfl_xor(s[j], off, 64);
            lse_merge(m[j], s[j], m2, s2);
        }
    }
    if (lr == 0) {
#pragma unroll
        for (int j = 0; j < 4; ++j) { red_m[w][lg * 4 + j] = m[j]; red_s[w][lg * 4 + j] = s[j]; }
    }
    __syncthreads();

    if (tid < 16) {
        int row = r0 + tid;
        if (row < PP) {
            float mm = red_m[0][tid], ss = red_s[0][tid];
#pragma unroll
            for (int ww = 1; ww < 8; ++ww) lse_merge(mm, ss, red_m[ww][tid], red_s[ww][tid]);
            out[(size_t)b * PP + row] = mm + logf(ss) - pos_lds[tid];
        }
    }
}

extern "C" void kernel_launch(void* const* d_in, const int* in_sizes, int n_in,
                              void* d_out, int out_size, void* d_ws, size_t ws_size,
                              hipStream_t stream) {
    const float* fq   = (const float*)d_in[0];
    const float* fk   = (const float*)d_in[1];
    const int*   sidx = (const int*)d_in[2];
    float* outp = (float*)d_out;

    char* p = (char*)d_ws;
    unsigned short* xqh = (unsigned short*)p; p += PLANE * 2;
    unsigned short* xql = (unsigned short*)p; p += PLANE * 2;
    unsigned short* xkh = (unsigned short*)p; p += PLANE * 2;
    unsigned short* xkl = (unsigned short*)p; p += PLANE * 2;
    short*          map = (short*)p;          p += (size_t)BB * HW * 2;
    short*      slotrec = (short*)p;          p += (size_t)BB * SRSTRIDE * 2;
    unsigned short* list = (unsigned short*)p; p += BB * NLINES * 2;
    unsigned int* bitmap = (unsigned int*)p;  p += BB * 32 * 4;
    int*         counts = (int*)p;            p += BB * 4;

    init_kernel<<<dim3(64), 256, 0, stream>>>((long long*)map, bitmap, counts);
    scatter_kernel<<<dim3((BB * PP + 255) / 256), 256, 0, stream>>>(sidx, map, bitmap);
    listslot_kernel<<<dim3(BB), 1024, 0, stream>>>(bitmap, map, list, slotrec, counts);
    gather_kernel<<<dim3(64, BB), 512, 0, stream>>>(fq, fk, list, slotrec, counts,
                                                    xqh, xql, xkh, xkl);
    nce_mfma<<<dim3(BB, RT), 512, 0, stream>>>(xqh, xql, xkh, xkl, outp);
}